// Round 7
// baseline (161.101 us; speedup 1.0000x reference)
//
#include <hip/hip_runtime.h>
#include <hip/hip_cooperative_groups.h>

namespace cg = cooperative_groups;

#define N_NODES 8192
#define DOUT    512
#define LOG2E   1.4426950408889634f
#define SQRT3   1.7320508075688772f

// ws float layout: aux[32] at 0   (G*log2e [0..8], g0*log2e [9..11], Cmax partials [12..19])
//                  T[512*8] at 32 (R3[3], h, M3[3], pad) — 128 B offset, 16B aligned
//
// Single cooperative kernel:
//   Phase 1 (block b): wave0 -> T row b; wave1 (b<12) -> aux[b]; wave2 (b<8) -> Cmax[b]
//   grid.sync()
//   Phase 2: identical to round-6 K3 (LDS-tiled softmax-weighted mean + fused epilogue)
__global__ __launch_bounds__(256) void k_fused(
    const float* __restrict__ nodes, const float* __restrict__ centre,
    const float* __restrict__ Wq, const float* __restrict__ bq,
    const float* __restrict__ Wk, const float* __restrict__ bk,
    const float* __restrict__ Wv, const float* __restrict__ bv,
    float* __restrict__ T, float* __restrict__ aux,
    float* __restrict__ out)
{
    __shared__ float lds[4096 * 3];   // 48 KB; stride-3 reads = 2-way bank alias (free)
    const int tid = threadIdx.x, lane = tid & 63, wv = tid >> 6;
    const int b = blockIdx.x;
    const float c0 = centre[0], c1 = centre[1], c2 = centre[2];

    // ---------------- Phase 1 ----------------
    if (wv == 0) {
        // T[b] = { R3 = Wk3[b] + Wv_k[b]@Wk3,  h = kc[b] + Wv_k[b].kc + Wv_q[b].u + bv[b],
        //          M3 = Wv_q[b]@Wq3 }
        const float* wvq = Wv + (size_t)b * 1024;   // Wv[b, :512]
        const float* wvk = wvq + 512;               // Wv[b, 512:]

        float m0=0.f,m1=0.f,m2=0.f,uc=0.f,r0=0.f,r1=0.f,r2=0.f,rc=0.f;
        for (int s = lane; s < 512; s += 64) {
            float a = wvq[s];
            float bb = wvk[s];
            float kcs = fmaf(Wk[s*6+3], c0, fmaf(Wk[s*6+4], c1,
                        fmaf(Wk[s*6+5], c2, bk[s])));
            float us  = fmaf(Wq[s*6+3], c0, fmaf(Wq[s*6+4], c1,
                        fmaf(Wq[s*6+5], c2, bq[s])));
            m0 = fmaf(a, Wq[s*6+0], m0);
            m1 = fmaf(a, Wq[s*6+1], m1);
            m2 = fmaf(a, Wq[s*6+2], m2);
            uc = fmaf(a, us, uc);
            r0 = fmaf(bb, Wk[s*6+0], r0);
            r1 = fmaf(bb, Wk[s*6+1], r1);
            r2 = fmaf(bb, Wk[s*6+2], r2);
            rc = fmaf(bb, kcs, rc);
        }
        #pragma unroll
        for (int off = 32; off; off >>= 1) {
            m0 += __shfl_xor(m0, off); m1 += __shfl_xor(m1, off);
            m2 += __shfl_xor(m2, off); uc += __shfl_xor(uc, off);
            r0 += __shfl_xor(r0, off); r1 += __shfl_xor(r1, off);
            r2 += __shfl_xor(r2, off); rc += __shfl_xor(rc, off);
        }
        if (lane == 0) {
            float kcr = fmaf(Wk[b*6+3], c0, fmaf(Wk[b*6+4], c1,
                        fmaf(Wk[b*6+5], c2, bk[b])));
            T[b*8+0] = Wk[b*6+0] + r0;
            T[b*8+1] = Wk[b*6+1] + r1;
            T[b*8+2] = Wk[b*6+2] + r2;
            T[b*8+3] = kcr + rc + uc + bv[b];
            T[b*8+4] = m0; T[b*8+5] = m1; T[b*8+6] = m2; T[b*8+7] = 0.f;
        }
    } else if (wv == 1 && b < 12) {
        // aux[b]: G = Wq3^T Wk3, g0 = Wq3^T kc (both *log2e)
        const int o = b;
        float acc = 0.f;
        if (o < 9) {
            int a = o / 3, c = o - a*3;
            for (int s = lane; s < 512; s += 64)
                acc = fmaf(Wq[s*6+a], Wk[s*6+c], acc);
        } else {
            int a = o - 9;
            for (int s = lane; s < 512; s += 64) {
                float kc = fmaf(Wk[s*6+3], c0, fmaf(Wk[s*6+4], c1,
                           fmaf(Wk[s*6+5], c2, bk[s])));
                acc = fmaf(Wq[s*6+a], kc, acc);
            }
        }
        #pragma unroll
        for (int off = 32; off; off >>= 1) acc += __shfl_xor(acc, off);
        if (lane == 0) aux[o] = acc * LOG2E;
    } else if (wv == 2 && b < 8) {
        // Cmax partial: max |component| over 1024 nodes (768 float4)
        const float4* src = (const float4*)nodes + (size_t)b * 768;
        float m = 0.f;
        for (int k = lane; k < 768; k += 64) {
            float4 v = src[k];
            m = fmaxf(m, fmaxf(fmaxf(fabsf(v.x), fabsf(v.y)),
                               fmaxf(fabsf(v.z), fabsf(v.w))));
        }
        #pragma unroll
        for (int off = 32; off; off >>= 1) m = fmaxf(m, __shfl_xor(m, off));
        if (lane == 0) aux[12 + b] = m;
    }

    cg::this_grid().sync();   // device-scope fence + grid barrier

    // ---------------- Phase 2 (identical to round-6 K3) ----------------
    const int ibase = (b * 4 + wv) * 4;

    const float G00=aux[0],G01=aux[1],G02=aux[2];
    const float G10=aux[3],G11=aux[4],G12=aux[5];
    const float G20=aux[6],G21=aux[7],G22=aux[8];
    const float g0=aux[9],g1=aux[10],g2=aux[11];
    float C = aux[12];
    #pragma unroll
    for (int p = 1; p < 8; ++p) C = fmaxf(C, aux[12+p]);
    const float Nbound = SQRT3 * C;   // |n_j| <= sqrt(3) * max|component|

    float nx_[4], ny_[4], nz_[4], vx[4], vy[4], vz[4], bb[4];
    float S[4], ax[4], ay[4], az[4];
    #pragma unroll
    for (int q = 0; q < 4; ++q) {
        int i = ibase + q;
        float x = nodes[3*i], y = nodes[3*i+1], z = nodes[3*i+2];
        nx_[q]=x; ny_[q]=y; nz_[q]=z;
        float a = fmaf(G00,x, fmaf(G01,y, fmaf(G02,z, g0)));
        float bq_ = fmaf(G10,x, fmaf(G11,y, fmaf(G12,z, g1)));
        float c = fmaf(G20,x, fmaf(G21,y, fmaf(G22,z, g2)));
        vx[q]=a; vy[q]=bq_; vz[q]=c;
        // Cauchy-Schwarz bound (log2 scale): arg <= ~0 always; shift cancels in softmax
        bb[q] = -sqrtf(fmaf(a,a, fmaf(bq_,bq_, c*c))) * Nbound;
        S[q]=0.f; ax[q]=0.f; ay[q]=0.f; az[q]=0.f;
    }

    for (int tile = 0; tile < 2; ++tile) {
        const float4* src = (const float4*)(nodes + tile*12288);  // 3072 float4 / tile
        float4* dst = (float4*)lds;
        for (int k = tid; k < 3072; k += 256) dst[k] = src[k];
        __syncthreads();
        for (int jj = lane; jj < 4096; jj += 64) {
            float nx = lds[jj*3+0], ny = lds[jj*3+1], nz = lds[jj*3+2];
            #pragma unroll
            for (int q = 0; q < 4; ++q) {
                float arg = fmaf(vx[q],nx, fmaf(vy[q],ny, fmaf(vz[q],nz, bb[q])));
                float e = exp2f(arg);
                S[q] += e;
                ax[q] = fmaf(e, nx, ax[q]);
                ay[q] = fmaf(e, ny, ay[q]);
                az[q] = fmaf(e, nz, az[q]);
            }
        }
        __syncthreads();
    }

    #pragma unroll
    for (int q = 0; q < 4; ++q) {
        #pragma unroll
        for (int off = 32; off; off >>= 1) {
            S[q]  += __shfl_xor(S[q],  off);
            ax[q] += __shfl_xor(ax[q], off);
            ay[q] += __shfl_xor(ay[q], off);
            az[q] += __shfl_xor(az[q], off);
        }
        float inv = 1.f / fmaxf(S[q], 1e-35f);
        ax[q] *= inv; ay[q] *= inv; az[q] *= inv;   // ā_i
    }

    // epilogue: out[i][d] = R3[d].n_i + M3[d].ā_i + h[d]; float2 stores (coalesced)
    const float4* T4 = (const float4*)T;
    #pragma unroll
    for (int t = 0; t < 4; ++t) {
        int d0 = t*128 + lane*2;
        float4 A0 = T4[2*d0+0], B0 = T4[2*d0+1];
        float4 A1 = T4[2*d0+2], B1 = T4[2*d0+3];
        #pragma unroll
        for (int q = 0; q < 4; ++q) {
            float v0 = fmaf(A0.x,nx_[q], fmaf(A0.y,ny_[q], fmaf(A0.z,nz_[q],
                       fmaf(B0.x,ax[q], fmaf(B0.y,ay[q], fmaf(B0.z,az[q], A0.w))))));
            float v1 = fmaf(A1.x,nx_[q], fmaf(A1.y,ny_[q], fmaf(A1.z,nz_[q],
                       fmaf(B1.x,ax[q], fmaf(B1.y,ay[q], fmaf(B1.z,az[q], A1.w))))));
            *(float2*)(out + (size_t)(ibase+q)*DOUT + d0) = make_float2(v0, v1);
        }
    }
}

extern "C" void kernel_launch(void* const* d_in, const int* in_sizes, int n_in,
                              void* d_out, int out_size, void* d_ws, size_t ws_size,
                              hipStream_t stream) {
    const float* nodes  = (const float*)d_in[0];
    const float* centre = (const float*)d_in[1];
    const float* Wq     = (const float*)d_in[2];
    const float* bq     = (const float*)d_in[3];
    const float* Wk     = (const float*)d_in[4];
    const float* bk     = (const float*)d_in[5];
    const float* Wv     = (const float*)d_in[6];
    const float* bv     = (const float*)d_in[7];

    float* ws  = (float*)(((uintptr_t)d_ws + 255) & ~(uintptr_t)255);
    float* aux = ws;        // 32 floats
    float* T   = ws + 32;   // 4096 floats, 128 B offset
    float* out = (float*)d_out;

    void* args[] = { (void*)&nodes, (void*)&centre, (void*)&Wq, (void*)&bq,
                     (void*)&Wk, (void*)&bk, (void*)&Wv, (void*)&bv,
                     (void*)&T, (void*)&aux, (void*)&out };
    hipLaunchCooperativeKernel((void*)k_fused, dim3(512), dim3(256),
                               args, 0, stream);
}

// Round 10
// 100.150 us; speedup vs baseline: 1.6086x; 1.6086x over previous
//
#include <hip/hip_runtime.h>

#define N_NODES 8192
#define DOUT    512
#define LOG2E   1.4426950408889634f
#define SQRT3   1.7320508075688772f

// raw v_exp_f32 (D = 2^S0) — single trans-pipe instruction, no libm, no builtins
__device__ __forceinline__ float exp2_raw(float x) {
    float r;
    asm("v_exp_f32 %0, %1" : "=v"(r) : "v"(x));
    return r;
}

// ws float layout: aux[32] at 0   (G*log2e [0..8], g0*log2e [9..11], Cmax partials [12..19])
//                  T[512*8] at 32 (R3[3], h, M3[3], pad) — 128 B offset, 16B aligned

// K2: blocks 0..511   -> epilogue table row T[r]
//     blocks 512..523 -> aux[o]: G = Wq3^T Wk3, g0 = Wq3^T kc (both *log2e)
//     blocks 524..531 -> aux[12+b]: partial max |node component| over 1024 nodes
__global__ __launch_bounds__(64) void k2_tables_aux(
    const float* __restrict__ nodes, const float* __restrict__ centre,
    const float* __restrict__ Wq, const float* __restrict__ bq,
    const float* __restrict__ Wk, const float* __restrict__ bk,
    const float* __restrict__ Wv, const float* __restrict__ bv,
    float* __restrict__ T, float* __restrict__ aux)
{
    const int r = blockIdx.x, lane = threadIdx.x;
    const float c0 = centre[0], c1 = centre[1], c2 = centre[2];

    if (r < 512) {
        // T[r] = { R3 = Wk3[r] + Wv_k[r]@Wk3,
        //          h  = kc[r] + Wv_k[r].kc + Wv_q[r].u + bv[r],
        //          M3 = Wv_q[r]@Wq3 }
        const float* wvq = Wv + (size_t)r * 1024;   // Wv[r, :512]
        const float* wvk = wvq + 512;               // Wv[r, 512:]

        float m0=0.f,m1=0.f,m2=0.f,uc=0.f,r0=0.f,r1=0.f,r2=0.f,rc=0.f;
        for (int s = lane; s < 512; s += 64) {
            float a = wvq[s];
            float b = wvk[s];
            float kcs = fmaf(Wk[s*6+3], c0, fmaf(Wk[s*6+4], c1,
                        fmaf(Wk[s*6+5], c2, bk[s])));
            float us  = fmaf(Wq[s*6+3], c0, fmaf(Wq[s*6+4], c1,
                        fmaf(Wq[s*6+5], c2, bq[s])));
            m0 = fmaf(a, Wq[s*6+0], m0);
            m1 = fmaf(a, Wq[s*6+1], m1);
            m2 = fmaf(a, Wq[s*6+2], m2);
            uc = fmaf(a, us, uc);
            r0 = fmaf(b, Wk[s*6+0], r0);
            r1 = fmaf(b, Wk[s*6+1], r1);
            r2 = fmaf(b, Wk[s*6+2], r2);
            rc = fmaf(b, kcs, rc);
        }
        #pragma unroll
        for (int off = 32; off; off >>= 1) {
            m0 += __shfl_xor(m0, off); m1 += __shfl_xor(m1, off);
            m2 += __shfl_xor(m2, off); uc += __shfl_xor(uc, off);
            r0 += __shfl_xor(r0, off); r1 += __shfl_xor(r1, off);
            r2 += __shfl_xor(r2, off); rc += __shfl_xor(rc, off);
        }
        if (lane == 0) {
            float kcr = fmaf(Wk[r*6+3], c0, fmaf(Wk[r*6+4], c1,
                        fmaf(Wk[r*6+5], c2, bk[r])));
            T[r*8+0] = Wk[r*6+0] + r0;
            T[r*8+1] = Wk[r*6+1] + r1;
            T[r*8+2] = Wk[r*6+2] + r2;
            T[r*8+3] = kcr + rc + uc + bv[r];
            T[r*8+4] = m0; T[r*8+5] = m1; T[r*8+6] = m2; T[r*8+7] = 0.f;
        }
    } else if (r < 524) {
        const int o = r - 512;   // 0..11
        float acc = 0.f;
        if (o < 9) {
            int a = o / 3, b = o - a*3;
            for (int s = lane; s < 512; s += 64)
                acc = fmaf(Wq[s*6+a], Wk[s*6+b], acc);
        } else {
            int a = o - 9;
            for (int s = lane; s < 512; s += 64) {
                float kc = fmaf(Wk[s*6+3], c0, fmaf(Wk[s*6+4], c1,
                           fmaf(Wk[s*6+5], c2, bk[s])));
                acc = fmaf(Wq[s*6+a], kc, acc);
            }
        }
        #pragma unroll
        for (int off = 32; off; off >>= 1) acc += __shfl_xor(acc, off);
        if (lane == 0) aux[o] = acc * LOG2E;
    } else {
        // partial max |component| over 1024 nodes (768 float4), one writer per slot
        const int b = r - 524;   // 0..7
        const float4* src = (const float4*)nodes + (size_t)b * 768;
        float m = 0.f;
        for (int k = lane; k < 768; k += 64) {
            float4 v = src[k];
            m = fmaxf(m, fmaxf(fmaxf(fabsf(v.x), fabsf(v.y)),
                               fmaxf(fabsf(v.z), fabsf(v.w))));
        }
        #pragma unroll
        for (int off = 32; off; off >>= 1) m = fmaxf(m, __shfl_xor(m, off));
        if (lane == 0) aux[12 + b] = m;
    }
}

// K3: per-row softmax-weighted mean node position + fused epilogue.
// 512 blocks x 256 threads (4 waves, 4 rows/wave); nodes staged through LDS in
// 4096-node tiles (48 KB static LDS). Hand-unrolled x2 j-loop, inline-asm exp2.
__global__ __launch_bounds__(256) void k3_attn(
    const float* __restrict__ nodes,
    const float* __restrict__ aux, const float* __restrict__ T,
    float* __restrict__ out)
{
    __shared__ float lds[4096 * 3];   // 48 KB; stride-3 reads = 2-way bank alias (free)
    const int tid = threadIdx.x, lane = tid & 63, wv = tid >> 6;
    const int ibase = (blockIdx.x * 4 + wv) * 4;

    const float G00=aux[0],G01=aux[1],G02=aux[2];
    const float G10=aux[3],G11=aux[4],G12=aux[5];
    const float G20=aux[6],G21=aux[7],G22=aux[8];
    const float g0=aux[9],g1=aux[10],g2=aux[11];
    float C = aux[12];
    #pragma unroll
    for (int b = 1; b < 8; ++b) C = fmaxf(C, aux[12+b]);
    const float Nbound = SQRT3 * C;   // |n_j| <= sqrt(3) * max|component|

    float nx_[4], ny_[4], nz_[4], vx[4], vy[4], vz[4], bb[4];
    float S[4], ax[4], ay[4], az[4];
    #pragma unroll
    for (int q = 0; q < 4; ++q) {
        int i = ibase + q;
        float x = nodes[3*i], y = nodes[3*i+1], z = nodes[3*i+2];
        nx_[q]=x; ny_[q]=y; nz_[q]=z;
        float a = fmaf(G00,x, fmaf(G01,y, fmaf(G02,z, g0)));
        float b = fmaf(G10,x, fmaf(G11,y, fmaf(G12,z, g1)));
        float c = fmaf(G20,x, fmaf(G21,y, fmaf(G22,z, g2)));
        vx[q]=a; vy[q]=b; vz[q]=c;
        // Cauchy-Schwarz bound (log2 scale): arg <= ~0 always; shift cancels in softmax
        bb[q] = -sqrtf(fmaf(a,a, fmaf(b,b, c*c))) * Nbound;
        S[q]=0.f; ax[q]=0.f; ay[q]=0.f; az[q]=0.f;
    }

    for (int tile = 0; tile < 2; ++tile) {
        const float4* src = (const float4*)(nodes + tile*12288);  // 3072 float4 / tile
        float4* dst = (float4*)lds;
        for (int k = tid; k < 3072; k += 256) dst[k] = src[k];
        __syncthreads();
        // hand-unrolled x2: 6 LDS reads batched per iteration, 2 independent exp chains
        for (int jj = lane; jj < 4096; jj += 128) {
            const int j2 = jj + 64;
            float nx0 = lds[jj*3+0], ny0 = lds[jj*3+1], nz0 = lds[jj*3+2];
            float nx1 = lds[j2*3+0], ny1 = lds[j2*3+1], nz1 = lds[j2*3+2];
            #pragma unroll
            for (int q = 0; q < 4; ++q) {
                float a0 = fmaf(vx[q],nx0, fmaf(vy[q],ny0, fmaf(vz[q],nz0, bb[q])));
                float a1 = fmaf(vx[q],nx1, fmaf(vy[q],ny1, fmaf(vz[q],nz1, bb[q])));
                float e0 = exp2_raw(a0);
                float e1 = exp2_raw(a1);
                S[q] += e0;
                ax[q] = fmaf(e0, nx0, ax[q]);
                ay[q] = fmaf(e0, ny0, ay[q]);
                az[q] = fmaf(e0, nz0, az[q]);
                S[q] += e1;
                ax[q] = fmaf(e1, nx1, ax[q]);
                ay[q] = fmaf(e1, ny1, ay[q]);
                az[q] = fmaf(e1, nz1, az[q]);
            }
        }
        __syncthreads();
    }

    #pragma unroll
    for (int q = 0; q < 4; ++q) {
        #pragma unroll
        for (int off = 32; off; off >>= 1) {
            S[q]  += __shfl_xor(S[q],  off);
            ax[q] += __shfl_xor(ax[q], off);
            ay[q] += __shfl_xor(ay[q], off);
            az[q] += __shfl_xor(az[q], off);
        }
        float inv = 1.f / fmaxf(S[q], 1e-35f);
        ax[q] *= inv; ay[q] *= inv; az[q] *= inv;   // ā_i
    }

    // epilogue: out[i][d] = R3[d].n_i + M3[d].ā_i + h[d]; float2 stores (coalesced)
    const float4* T4 = (const float4*)T;
    #pragma unroll
    for (int t = 0; t < 4; ++t) {
        int d0 = t*128 + lane*2;
        float4 A0 = T4[2*d0+0], B0 = T4[2*d0+1];
        float4 A1 = T4[2*d0+2], B1 = T4[2*d0+3];
        #pragma unroll
        for (int q = 0; q < 4; ++q) {
            float v0 = fmaf(A0.x,nx_[q], fmaf(A0.y,ny_[q], fmaf(A0.z,nz_[q],
                       fmaf(B0.x,ax[q], fmaf(B0.y,ay[q], fmaf(B0.z,az[q], A0.w))))));
            float v1 = fmaf(A1.x,nx_[q], fmaf(A1.y,ny_[q], fmaf(A1.z,nz_[q],
                       fmaf(B1.x,ax[q], fmaf(B1.y,ay[q], fmaf(B1.z,az[q], A1.w))))));
            *(float2*)(out + (size_t)(ibase+q)*DOUT + d0) = make_float2(v0, v1);
        }
    }
}

extern "C" void kernel_launch(void* const* d_in, const int* in_sizes, int n_in,
                              void* d_out, int out_size, void* d_ws, size_t ws_size,
                              hipStream_t stream) {
    const float* nodes  = (const float*)d_in[0];
    const float* centre = (const float*)d_in[1];
    const float* Wq     = (const float*)d_in[2];
    const float* bq     = (const float*)d_in[3];
    const float* Wk     = (const float*)d_in[4];
    const float* bk     = (const float*)d_in[5];
    const float* Wv     = (const float*)d_in[6];
    const float* bv     = (const float*)d_in[7];

    float* ws  = (float*)(((uintptr_t)d_ws + 255) & ~(uintptr_t)255);
    float* aux = ws;        // 32 floats
    float* T   = ws + 32;   // 4096 floats, 128 B offset
    float* out = (float*)d_out;

    hipLaunchKernelGGL(k2_tables_aux, dim3(532), dim3(64), 0, stream,
                       nodes, centre, Wq, bq, Wk, bk, Wv, bv, T, aux);
    hipLaunchKernelGGL(k3_attn,       dim3(512), dim3(256), 0, stream,
                       nodes, aux, T, out);
}